// Round 6
// baseline (786.466 us; speedup 1.0000x reference)
//
#include <hip/hip_runtime.h>
#include <math.h>

// ArcFaceLoss: B=512, D=512, C=100000, margin=0.5, scale=64
// v6:
//   - prep_w v2: register-stash, fully-coalesced normalize+pack (v5's version wrote
//     8B granules scattered across 16 chunks -> ~25% write efficiency, ~100us).
//     8 threads/row, 16 float4 in regs, shfl sumsq, dense 64B-segment stores.
//     Emits 128-class tiles (8 KB per chunk) for the retiled gemm.
//   - gemm_lse v6: block = 256 rows x 128 classes (wave tile unchanged 64x64,
//     identical chunk body: 4+4 ds_read_b128 + 16 MFMA + 1 barrier). LDS 48 KB
//     -> 3 blocks/CU (24 waves/CU) to hide the per-chunk vmcnt/barrier drain.
//   - REP=64 gsum replicas, finalize unchanged.

#define NB 512
#define ND 512
#define NC 100000
#define BK 32
#define NCHUNK 16          // ND / BK
#define CT 64              // classes per block (fallback kernel)
#define NTILE 1563         // fallback grid
#define CTW 128            // classes per gemm block (v6)
#define NTW 782            // class tiles (v6): 782*128 = 100096
#define WPT (NCHUNK * 8192)  // bytes per 128-class tile = 131072
#define REP 64             // gsum replicas (atomic decongestion)
#define FSCALE 64.0f
#define C_COS_M 0.8775825618903728f
#define C_SIN_M 0.479425538604203f
#define C_TH  (-0.8775825618903728f)   // cos(pi - m)
#define C_MM  0.2397127693021015f      // sin(pi - m) * m

// Tile swizzle (proven v3/v4/v5): slot bits [5:4] ^= bits [8:7] (= row bits 1:2
// for 64B rows). Involutive, preserves bits [3:0]. Column-reads -> 2-way (free).
#define SWZA(b) ((b) ^ (((b) >> 3) & 48))
// v4-fallback W swizzle (fp32 rows, 128 B)
#define SWZW(b) ((b) ^ (((b) >> 3) & 112))

typedef __bf16 bf16x8 __attribute__((ext_vector_type(8)));
typedef __bf16 bf16x4 __attribute__((ext_vector_type(4)));
typedef float  f32x4  __attribute__((ext_vector_type(4)));
typedef __attribute__((address_space(1))) unsigned int GU;
typedef __attribute__((address_space(3))) unsigned int LU;

// ---------------- 1) normalize + pack x (swizzled chunk-major, unchanged) ----------------
__global__ void pack_x_kernel(const float* __restrict__ x, __bf16* __restrict__ xp) {
  const int b = blockIdx.x;
  const int t = threadIdx.x;                   // 0..127
  float4 v = reinterpret_cast<const float4*>(x + (size_t)b * ND)[t];
  float ss = v.x*v.x + v.y*v.y + v.z*v.z + v.w*v.w;
  #pragma unroll
  for (int m = 1; m < 64; m <<= 1) ss += __shfl_xor(ss, m);
  __shared__ float sred[2];
  if ((t & 63) == 0) sred[t >> 6] = ss;
  __syncthreads();
  const float rn = rsqrtf(fmaxf(sred[0] + sred[1], 1e-24f));
  bf16x4 o;
  o[0] = (__bf16)(v.x * rn); o[1] = (__bf16)(v.y * rn);
  o[2] = (__bf16)(v.z * rn); o[3] = (__bf16)(v.w * rn);
  const int k = 4 * t;                         // element index 0..508
  const int chunk = k >> 5;
  const int lb = b * 64 + (k & 31) * 2;        // logical byte within 32KB chunk-block
  char* dst = (char*)xp + (size_t)chunk * (NB * BK * 2) + SWZA(lb);
  *reinterpret_cast<bf16x4*>(dst) = o;
}

// ---------------- 1b) normalize + pack w (v2: register stash, coalesced) ----------------
// Block: 512 threads = 64 rows x 8 parts. Thread reads 16 float4 (dense 128B runs
// per wave), shfl-reduces sumsq over the 8 parts, then stores 16x bf16x4: per
// instruction a wave writes 8 complete 64B row-segments (SWZA permutes 16B slots
// only WITHIN a segment) -> fully dense write transactions.
__global__ __launch_bounds__(512) void prep_w_kernel(const float* __restrict__ w,
                                                     __bf16* __restrict__ wp) {
  const int t    = threadIdx.x;
  const int row  = blockIdx.x * 64 + (t >> 3);
  const int part = t & 7;
  const int srow = min(row, NC - 1);
  const float4* src = reinterpret_cast<const float4*>(w + (size_t)srow * ND);
  float4 v[16];
  float ss = 0.f;
  #pragma unroll
  for (int j = 0; j < 16; ++j) {
    v[j] = src[j * 8 + part];
    ss += v[j].x*v[j].x + v[j].y*v[j].y + v[j].z*v[j].z + v[j].w*v[j].w;
  }
  ss += __shfl_xor(ss, 1);
  ss += __shfl_xor(ss, 2);
  ss += __shfl_xor(ss, 4);
  float rn = rsqrtf(fmaxf(ss, 1e-24f));
  if (row >= NC) rn = 0.f;                     // zero pad rows
  const int tile = row >> 7;
  const int lrow = row & 127;
  char* base = (char*)wp + (size_t)tile * WPT;
  const int slot = SWZA(lrow * 64 + part * 8); // 8B-aligned (SWZA keeps bits 3:0)
  #pragma unroll
  for (int j = 0; j < 16; ++j) {               // chunk == j for this mapping
    bf16x4 o;
    o[0] = (__bf16)(v[j].x * rn); o[1] = (__bf16)(v[j].y * rn);
    o[2] = (__bf16)(v[j].z * rn); o[3] = (__bf16)(v[j].w * rn);
    *reinterpret_cast<bf16x4*>(base + j * 8192 + slot) = o;
  }
}

// ---------------- 2) fp32-accurate target cosine + phi (unchanged) ----------------
__global__ void cosphi_kernel(const float* __restrict__ x, const float* __restrict__ w,
                              const int* __restrict__ tgt,
                              float* __restrict__ cos_t, float* __restrict__ phi_t) {
  const int b = blockIdx.x;
  const int lane = threadIdx.x;                // 0..63
  const int t = tgt[b];
  const float4* xr = reinterpret_cast<const float4*>(x + (size_t)b * ND);
  const float4* wr = reinterpret_cast<const float4*>(w + (size_t)t * ND);
  float dp = 0.f, xs = 0.f, ws = 0.f;
  #pragma unroll
  for (int j = 0; j < 2; ++j) {
    float4 xv = xr[lane * 2 + j];
    float4 wv = wr[lane * 2 + j];
    dp += xv.x*wv.x + xv.y*wv.y + xv.z*wv.z + xv.w*wv.w;
    xs += xv.x*xv.x + xv.y*xv.y + xv.z*xv.z + xv.w*xv.w;
    ws += wv.x*wv.x + wv.y*wv.y + wv.z*wv.z + wv.w*wv.w;
  }
  #pragma unroll
  for (int m = 1; m < 64; m <<= 1) {
    dp += __shfl_xor(dp, m);
    xs += __shfl_xor(xs, m);
    ws += __shfl_xor(ws, m);
  }
  if (lane == 0) {
    float c = dp * rsqrtf(fmaxf(xs, 1e-24f)) * rsqrtf(fmaxf(ws, 1e-24f));
    c = fminf(fmaxf(c, -1.f), 1.f);
    float s = sqrtf(fmaxf(1.f - c * c, 0.f));
    float phi = c * C_COS_M - s * C_SIN_M;
    phi = (c > C_TH) ? phi : (c - C_MM);
    cos_t[b] = c;
    phi_t[b] = phi;
  }
}

// ---------------- 3) fused GEMM + partial sum-exp (v6: 256x128 tile, 3 blk/CU) -------
// 512 threads = 8 waves (wr = wv>>1 in 0..3, wc = wv&1 in 0..1). Block bid:
// class tile = bid>>1 (128 classes), row half rh = bid&1 (256 batch rows).
// Wave tile 64 rows x 64 classes: 4x4 frags, per chunk 4+4 ds_read_b128 + 16 MFMA.
// LDS: A 2x16KB + W 2x8KB = 48 KB -> 3 blocks/CU (24 waves/CU).
__global__ __launch_bounds__(512, 6) void gemm_lse_kernel(
    const __bf16* __restrict__ xp, const __bf16* __restrict__ wp,
    float* __restrict__ gsum) {
  __shared__ __align__(16) char As[2 * 16384];   // 2 x 16 KB (swizzled)
  __shared__ __align__(16) char Ws[2 * 8192];    // 2 x 8 KB  (swizzled)

  const int tid  = threadIdx.x;
  const int wv   = tid >> 6;          // 0..7
  const int lane = tid & 63;
  const int tile = blockIdx.x >> 1;
  const int rh   = blockIdx.x & 1;
  const int bc   = tile * CTW;

  const char* ag = (const char*)xp + rh * 16384 + wv * 1024 + lane * 16;
  const char* wg = (const char*)wp + (size_t)tile * WPT + wv * 1024 + lane * 16;

  // ---- prologue: stage chunk 0 ----
  {
    __builtin_amdgcn_global_load_lds((const GU*)wg, (LU*)(Ws + wv * 1024), 16, 0, 0);
    char* la = As + wv * 1024;
    __builtin_amdgcn_global_load_lds((const GU*)ag, (LU*)la, 16, 0, 0);
    __builtin_amdgcn_global_load_lds((const GU*)(ag + 8192), (LU*)(la + 8192),
                                     16, 0, 0);
  }

  // ---- fragment offsets (loop-invariant, swizzled) ----
  const int wr   = wv >> 1;           // 0..3 (row quarter)
  const int wc   = wv & 1;            // 0..1 (class half)
  const int ra   = lane & 15;
  const int quad = lane >> 4;
  int aoff[4], boff[4];
  #pragma unroll
  for (int rt = 0; rt < 4; ++rt)
    aoff[rt] = SWZA((wr * 64 + rt * 16 + ra) * 64 + quad * 16);
  #pragma unroll
  for (int ct = 0; ct < 4; ++ct)
    boff[ct] = SWZA((wc * 64 + ct * 16 + ra) * 64 + quad * 16);

  f32x4 acc[4][4] = {};

  __syncthreads();

  for (int c = 0; c < NCHUNK; ++c) {
    const int cur = c & 1;
    if (c + 1 < NCHUNK) {
      __builtin_amdgcn_global_load_lds(
          (const GU*)(wg + (size_t)(c + 1) * 8192),
          (LU*)(Ws + (cur ^ 1) * 8192 + wv * 1024), 16, 0, 0);
      const char* a1 = ag + (size_t)(c + 1) * 32768;
      char* la = As + (cur ^ 1) * 16384 + wv * 1024;
      __builtin_amdgcn_global_load_lds((const GU*)a1, (LU*)la, 16, 0, 0);
      __builtin_amdgcn_global_load_lds((const GU*)(a1 + 8192), (LU*)(la + 8192),
                                       16, 0, 0);
    }

    const char* asb = As + cur * 16384;
    const char* wsb = Ws + cur * 8192;
    bf16x8 af[4], bfr[4];
    #pragma unroll
    for (int rt = 0; rt < 4; ++rt)
      af[rt] = *reinterpret_cast<const bf16x8*>(asb + aoff[rt]);
    #pragma unroll
    for (int ct = 0; ct < 4; ++ct)
      bfr[ct] = *reinterpret_cast<const bf16x8*>(wsb + boff[ct]);
    #pragma unroll
    for (int rt = 0; rt < 4; ++rt)
      #pragma unroll
      for (int ct = 0; ct < 4; ++ct)
        acc[rt][ct] = __builtin_amdgcn_mfma_f32_16x16x32_bf16(af[rt], bfr[ct],
                                                              acc[rt][ct], 0, 0, 0);
    __syncthreads();   // publishes buffers cur^1 (vmcnt+lgkm drained)
  }

  // ---- epilogue: acc IS cosine; e = exp(64*cos - 64); class-sum; replica atomic ----
  // C/D layout (16x16): col = lane&15 (class), row = quad*4 + reg
  int vmask[4];
  #pragma unroll
  for (int ct = 0; ct < 4; ++ct)
    vmask[ct] = (bc + wc * 64 + ct * 16 + ra) < NC;
  float* gs = gsum + (size_t)(blockIdx.x & (REP - 1)) * NB;
  const int rbase = rh * 256 + wr * 64;
  #pragma unroll
  for (int rt = 0; rt < 4; ++rt) {
    #pragma unroll
    for (int rg = 0; rg < 4; ++rg) {
      float es = 0.f;
      #pragma unroll
      for (int ct = 0; ct < 4; ++ct) {
        float e = __expf(fmaf(FSCALE, acc[rt][ct][rg], -FSCALE));
        es += vmask[ct] ? e : 0.f;
      }
      es += __shfl_xor(es, 1);
      es += __shfl_xor(es, 2);
      es += __shfl_xor(es, 4);
      es += __shfl_xor(es, 8);
      if (ra == 0) {
        atomicAdd(&gs[rbase + rt * 16 + quad * 4 + rg], es);
      }
    }
  }
}

// ---------------- 3-fallback) v4 kernel (fp32 W streaming) — used only if ws small ----
__global__ __launch_bounds__(512, 4) void gemm_lse_fb(
    const __bf16* __restrict__ xp, const float* __restrict__ w,
    float* __restrict__ gsum) {
  __shared__ __align__(16) char As[2 * NB * BK * 2];
  __shared__ __align__(16) char Ws[2 * CT * BK * 4];
  const int tid  = threadIdx.x;
  const int wv   = tid >> 6;
  const int lane = tid & 63;
  const int bc   = blockIdx.x * CT;
  const int p_w  = wv * 1024 + lane * 16;
  const int lbw  = SWZW(p_w);
  const int wrow = min(bc + (lbw >> 7), NC - 1);
  const char* wg = (const char*)w + (size_t)wrow * (ND * 4) + (lbw & 127);
  const char* ag = (const char*)xp + wv * 1024 + lane * 16;
  {
    char* la = As + wv * 1024;
    #pragma unroll
    for (int j = 0; j < 4; ++j)
      __builtin_amdgcn_global_load_lds((const GU*)(ag + j * 8192),
                                       (LU*)(la + j * 8192), 16, 0, 0);
    __builtin_amdgcn_global_load_lds((const GU*)wg, (LU*)(Ws + wv * 1024), 16, 0, 0);
  }
  const int m_w = wv * 64;
  const int ra = lane & 15;
  const int quad = lane >> 4;
  int aoff[4], woff[4];
  #pragma unroll
  for (int rt = 0; rt < 4; ++rt)
    aoff[rt] = SWZA((m_w + rt * 16 + ra) * 64 + quad * 16);
  #pragma unroll
  for (int ct = 0; ct < 4; ++ct)
    woff[ct] = SWZW((ct * 16 + ra) * 128 + quad * 32);
  f32x4 acc[4][4] = {};
  float wsq[4] = {0.f, 0.f, 0.f, 0.f};
  __syncthreads();
  for (int c = 0; c < NCHUNK; ++c) {
    const int cur = c & 1;
    if (c + 1 < NCHUNK) {
      const char* a1 = ag + (size_t)(c + 1) * (NB * BK * 2);
      char* la = As + (cur ^ 1) * (NB * BK * 2) + wv * 1024;
      #pragma unroll
      for (int j = 0; j < 4; ++j)
        __builtin_amdgcn_global_load_lds((const GU*)(a1 + j * 8192),
                                         (LU*)(la + j * 8192), 16, 0, 0);
      __builtin_amdgcn_global_load_lds((const GU*)(wg + (size_t)(c + 1) * 128),
                                       (LU*)(Ws + (cur ^ 1) * 8192 + wv * 1024),
                                       16, 0, 0);
    }
    const char* asb = As + cur * (NB * BK * 2);
    const char* wsb = Ws + cur * 8192;
    bf16x8 af[4];
    #pragma unroll
    for (int rt = 0; rt < 4; ++rt)
      af[rt] = *reinterpret_cast<const bf16x8*>(asb + aoff[rt]);
    #pragma unroll
    for (int ct = 0; ct < 4; ++ct) {
      float4 w0 = *reinterpret_cast<const float4*>(wsb + woff[ct]);
      float4 w1 = *reinterpret_cast<const float4*>(wsb + woff[ct] + 16);
      wsq[ct] += w0.x*w0.x + w0.y*w0.y + w0.z*w0.z + w0.w*w0.w
               + w1.x*w1.x + w1.y*w1.y + w1.z*w1.z + w1.w*w1.w;
      bf16x8 bfr;
      bfr[0] = (__bf16)w0.x; bfr[1] = (__bf16)w0.y;
      bfr[2] = (__bf16)w0.z; bfr[3] = (__bf16)w0.w;
      bfr[4] = (__bf16)w1.x; bfr[5] = (__bf16)w1.y;
      bfr[6] = (__bf16)w1.z; bfr[7] = (__bf16)w1.w;
      #pragma unroll
      for (int rt = 0; rt < 4; ++rt)
        acc[rt][ct] = __builtin_amdgcn_mfma_f32_16x16x32_bf16(af[rt], bfr,
                                                              acc[rt][ct], 0, 0, 0);
    }
    __syncthreads();
  }
  float rnw[4];
  int vmask[4];
  #pragma unroll
  for (int ct = 0; ct < 4; ++ct) {
    wsq[ct] += __shfl_xor(wsq[ct], 16);
    wsq[ct] += __shfl_xor(wsq[ct], 32);
    rnw[ct] = rsqrtf(fmaxf(wsq[ct], 1e-24f));
    vmask[ct] = (bc + ct * 16 + ra) < NC;
  }
  float* gs = gsum + (size_t)(blockIdx.x & (REP - 1)) * NB;
  #pragma unroll
  for (int rt = 0; rt < 4; ++rt) {
    #pragma unroll
    for (int rg = 0; rg < 4; ++rg) {
      float es = 0.f;
      #pragma unroll
      for (int ct = 0; ct < 4; ++ct) {
        float cosv = acc[rt][ct][rg] * rnw[ct];
        float e = __expf(fmaf(FSCALE, cosv, -FSCALE));
        es += vmask[ct] ? e : 0.f;
      }
      es += __shfl_xor(es, 1);
      es += __shfl_xor(es, 2);
      es += __shfl_xor(es, 4);
      es += __shfl_xor(es, 8);
      if (ra == 0) atomicAdd(&gs[m_w + rt * 16 + quad * 4 + rg], es);
    }
  }
}

// ---------------- 4) finalize (sums REP replicas) ----------------
__global__ void finalize_kernel(const float* __restrict__ gsum,
                                const float* __restrict__ cos_t,
                                const float* __restrict__ phi_t,
                                float* __restrict__ out) {
  const int b = threadIdx.x;   // 512
  float s = 0.f;
  #pragma unroll 8
  for (int r = 0; r < REP; ++r) s += gsum[r * NB + b];
  const float c = cos_t[b];
  const float p = phi_t[b];
  float corr = s - __expf(fmaf(FSCALE, c, -FSCALE))
                 + __expf(fmaf(FSCALE, p, -FSCALE));
  corr = fmaxf(corr, 1e-38f);
  float lb = FSCALE + logf(corr) - FSCALE * p;
  #pragma unroll
  for (int m = 1; m < 64; m <<= 1) lb += __shfl_xor(lb, m);
  __shared__ float pr[8];
  if ((b & 63) == 0) pr[b >> 6] = lb;
  __syncthreads();
  if (b == 0) {
    float tot = 0.f;
    #pragma unroll
    for (int j = 0; j < 8; ++j) tot += pr[j];
    out[0] = tot * (1.0f / NB);
  }
}

extern "C" void kernel_launch(void* const* d_in, const int* in_sizes, int n_in,
                              void* d_out, int out_size, void* d_ws, size_t ws_size,
                              hipStream_t stream) {
  const float* x  = (const float*)d_in[0];
  const float* w  = (const float*)d_in[1];
  const int* tgt  = (const int*)d_in[2];
  float* out      = (float*)d_out;

  // workspace: xp (512K) | gsum (128K) | cos_t/phi_t (4K) | [1MB:] wp (102.5M)
  __bf16* xp   = (__bf16*)d_ws;
  float* gsum  = (float*)((char*)d_ws + (size_t)NB * ND * 2);
  float* cos_t = gsum + (size_t)REP * NB;
  float* phi_t = cos_t + NB;
  const size_t WPOFF   = 1 << 20;
  const size_t WPBYTES = (size_t)NTW * WPT;   // 102,498,304
  __bf16* wp = (__bf16*)((char*)d_ws + WPOFF);

  hipMemsetAsync(gsum, 0, (size_t)REP * NB * sizeof(float), stream);
  pack_x_kernel<<<NB, 128, 0, stream>>>(x, xp);
  cosphi_kernel<<<NB, 64, 0, stream>>>(x, w, tgt, cos_t, phi_t);
  if (ws_size >= WPOFF + WPBYTES) {
    prep_w_kernel<<<(NTW * CTW) / 64, 512, 0, stream>>>(w, wp);   // 1564 blocks
    gemm_lse_kernel<<<NTW * 2, 512, 0, stream>>>(xp, wp, gsum);   // 1564 blocks
  } else {
    gemm_lse_fb<<<NTILE, 512, 0, stream>>>(xp, w, gsum);
  }
  finalize_kernel<<<1, 512, 0, stream>>>(gsum, cos_t, phi_t, out);
}

// Round 7
// 395.567 us; speedup vs baseline: 1.9882x; 1.9882x over previous
//
#include <hip/hip_runtime.h>
#include <math.h>

// ArcFaceLoss: B=512, D=512, C=100000, margin=0.5, scale=64
// v7 = v5 gemm (proven: CT=64, full-xp block, FETCH ~110MB, conflicts 0)
//      + coalesced prep_w v2 retargeted to 64-class tiles.
// v6 retile reverted: halving A-tiles + 3 blk/CU thrashed per-XCD L2 ->
// FETCH 640MB (zero absorption), gemm BW-bound at 505us.

#define NB 512
#define ND 512
#define NC 100000
#define BK 32
#define NCHUNK 16          // ND / BK
#define CT 64              // classes per block
#define NTILE 1563         // ceil(NC / CT); padded classes = 100032
#define REP 64             // gsum replicas (atomic decongestion)
#define FSCALE 64.0f
#define C_COS_M 0.8775825618903728f
#define C_SIN_M 0.479425538604203f
#define C_TH  (-0.8775825618903728f)   // cos(pi - m)
#define C_MM  0.2397127693021015f      // sin(pi - m) * m

// Tile swizzle (proven v3-v6, conflicts==0): slot bits [5:4] ^= bits [8:7]
// (= row bits 1:2 for 64B rows). Involutive, preserves bits [3:0].
#define SWZA(b) ((b) ^ (((b) >> 3) & 48))
// fallback W swizzle (fp32 rows, 128 B)
#define SWZW(b) ((b) ^ (((b) >> 3) & 112))

typedef __bf16 bf16x8 __attribute__((ext_vector_type(8)));
typedef __bf16 bf16x4 __attribute__((ext_vector_type(4)));
typedef float  f32x4  __attribute__((ext_vector_type(4)));
typedef __attribute__((address_space(1))) unsigned int GU;
typedef __attribute__((address_space(3))) unsigned int LU;

// ---------------- 1) normalize + pack x (swizzled chunk-major, unchanged) ----------------
__global__ void pack_x_kernel(const float* __restrict__ x, __bf16* __restrict__ xp) {
  const int b = blockIdx.x;
  const int t = threadIdx.x;                   // 0..127
  float4 v = reinterpret_cast<const float4*>(x + (size_t)b * ND)[t];
  float ss = v.x*v.x + v.y*v.y + v.z*v.z + v.w*v.w;
  #pragma unroll
  for (int m = 1; m < 64; m <<= 1) ss += __shfl_xor(ss, m);
  __shared__ float sred[2];
  if ((t & 63) == 0) sred[t >> 6] = ss;
  __syncthreads();
  const float rn = rsqrtf(fmaxf(sred[0] + sred[1], 1e-24f));
  bf16x4 o;
  o[0] = (__bf16)(v.x * rn); o[1] = (__bf16)(v.y * rn);
  o[2] = (__bf16)(v.z * rn); o[3] = (__bf16)(v.w * rn);
  const int k = 4 * t;                         // element index 0..508
  const int chunk = k >> 5;
  const int lb = b * 64 + (k & 31) * 2;        // logical byte within 32KB chunk-block
  char* dst = (char*)xp + (size_t)chunk * (NB * BK * 2) + SWZA(lb);
  *reinterpret_cast<bf16x4*>(dst) = o;
}

// ---------------- 1b) normalize + pack w (coalesced, 64-class tiles) ----------------
// Block: 512 threads = 64 rows x 8 parts, tile = blockIdx.x. Thread reads 16 float4
// (8 threads cover one row: dense 128B runs), shfl-reduces sumsq over the 8 parts,
// stores 16x bf16x4: per store instruction a wave writes 8 complete 64B row
// segments (SWZA permutes 16B slots only WITHIN a segment) = 512 B dense.
// Layout written == v5/v7 gemm reader: wp + tile*65536 + chunk*4096
//                                      + SWZA(lrow*64 + (k&31)*2)
__global__ __launch_bounds__(512) void prep_w_kernel(const float* __restrict__ w,
                                                     __bf16* __restrict__ wp) {
  const int t    = threadIdx.x;
  const int row  = blockIdx.x * 64 + (t >> 3);
  const int part = t & 7;
  const int srow = min(row, NC - 1);
  const float4* src = reinterpret_cast<const float4*>(w + (size_t)srow * ND);
  float4 v[16];
  float ss = 0.f;
  #pragma unroll
  for (int j = 0; j < 16; ++j) {
    v[j] = src[j * 8 + part];                  // element k = 32j + 4*part -> chunk j
    ss += v[j].x*v[j].x + v[j].y*v[j].y + v[j].z*v[j].z + v[j].w*v[j].w;
  }
  ss += __shfl_xor(ss, 1);
  ss += __shfl_xor(ss, 2);
  ss += __shfl_xor(ss, 4);
  float rn = rsqrtf(fmaxf(ss, 1e-24f));
  if (row >= NC) rn = 0.f;                     // zero pad rows
  const int lrow = row & 63;
  char* base = (char*)wp + (size_t)blockIdx.x * (NCHUNK * 4096);
  const int slot = SWZA(lrow * 64 + part * 8); // 8B-aligned (SWZA keeps bits 3:0)
  #pragma unroll
  for (int j = 0; j < 16; ++j) {
    bf16x4 o;
    o[0] = (__bf16)(v[j].x * rn); o[1] = (__bf16)(v[j].y * rn);
    o[2] = (__bf16)(v[j].z * rn); o[3] = (__bf16)(v[j].w * rn);
    *reinterpret_cast<bf16x4*>(base + j * 4096 + slot) = o;
  }
}

// ---------------- 2) fp32-accurate target cosine + phi (unchanged) ----------------
__global__ void cosphi_kernel(const float* __restrict__ x, const float* __restrict__ w,
                              const int* __restrict__ tgt,
                              float* __restrict__ cos_t, float* __restrict__ phi_t) {
  const int b = blockIdx.x;
  const int lane = threadIdx.x;                // 0..63
  const int t = tgt[b];
  const float4* xr = reinterpret_cast<const float4*>(x + (size_t)b * ND);
  const float4* wr = reinterpret_cast<const float4*>(w + (size_t)t * ND);
  float dp = 0.f, xs = 0.f, ws = 0.f;
  #pragma unroll
  for (int j = 0; j < 2; ++j) {
    float4 xv = xr[lane * 2 + j];
    float4 wv = wr[lane * 2 + j];
    dp += xv.x*wv.x + xv.y*wv.y + xv.z*wv.z + xv.w*wv.w;
    xs += xv.x*xv.x + xv.y*xv.y + xv.z*xv.z + xv.w*xv.w;
    ws += wv.x*wv.x + wv.y*wv.y + wv.z*wv.z + wv.w*wv.w;
  }
  #pragma unroll
  for (int m = 1; m < 64; m <<= 1) {
    dp += __shfl_xor(dp, m);
    xs += __shfl_xor(xs, m);
    ws += __shfl_xor(ws, m);
  }
  if (lane == 0) {
    float c = dp * rsqrtf(fmaxf(xs, 1e-24f)) * rsqrtf(fmaxf(ws, 1e-24f));
    c = fminf(fmaxf(c, -1.f), 1.f);
    float s = sqrtf(fmaxf(1.f - c * c, 0.f));
    float phi = c * C_COS_M - s * C_SIN_M;
    phi = (c > C_TH) ? phi : (c - C_MM);
    cos_t[b] = c;
    phi_t[b] = phi;
  }
}

// ---------------- 3) fused GEMM + partial sum-exp (v5 structure, verbatim) ----------
// 512 threads = 8 waves. Wave wv owns rows [64wv, 64wv+64) x 64 classes (4x4 frags).
// Per chunk: glds A(c+1) (4/wave) + glds W(c+1) (1, waves 0-3) -> 4+4 ds_read_b128
// -> 16 MFMA -> barrier. No VALU in loop; MFMA output is cosine directly.
__global__ __launch_bounds__(512, 4) void gemm_lse_kernel(
    const __bf16* __restrict__ xp, const __bf16* __restrict__ wp,
    float* __restrict__ gsum) {
  __shared__ __align__(16) char As[2 * NB * BK * 2];   // 2 x 32 KB (swizzled)
  __shared__ __align__(16) char Ws[2 * CT * BK * 2];   // 2 x 4 KB  (swizzled)

  const int tid  = threadIdx.x;
  const int wv   = tid >> 6;          // 0..7
  const int lane = tid & 63;
  const int bc   = blockIdx.x * CT;

  const char* ag = (const char*)xp + wv * 1024 + lane * 16;
  const char* wg = (const char*)wp + (size_t)blockIdx.x * (NCHUNK * 4096)
                   + wv * 1024 + lane * 16;    // waves 0-3 only

  // ---- prologue: stage chunk 0 ----
  {
    char* la = As + wv * 1024;
    #pragma unroll
    for (int j = 0; j < 4; ++j)
      __builtin_amdgcn_global_load_lds((const GU*)(ag + j * 8192),
                                       (LU*)(la + j * 8192), 16, 0, 0);
    if (wv < 4)
      __builtin_amdgcn_global_load_lds((const GU*)wg, (LU*)(Ws + wv * 1024),
                                       16, 0, 0);
  }

  // ---- fragment offsets (loop-invariant, swizzled) ----
  const int m_w  = wv * 64;
  const int ra   = lane & 15;
  const int quad = lane >> 4;
  int aoff[4], boff[4];
  #pragma unroll
  for (int rt = 0; rt < 4; ++rt)
    aoff[rt] = SWZA((m_w + rt * 16 + ra) * 64 + quad * 16);
  #pragma unroll
  for (int ct = 0; ct < 4; ++ct)
    boff[ct] = SWZA((ct * 16 + ra) * 64 + quad * 16);

  f32x4 acc[4][4] = {};

  __syncthreads();

  for (int c = 0; c < NCHUNK; ++c) {
    const int cur = c & 1;
    if (c + 1 < NCHUNK) {
      const char* a1 = ag + (size_t)(c + 1) * (NB * BK * 2);
      char* la = As + (cur ^ 1) * (NB * BK * 2) + wv * 1024;
      #pragma unroll
      for (int j = 0; j < 4; ++j)
        __builtin_amdgcn_global_load_lds((const GU*)(a1 + j * 8192),
                                         (LU*)(la + j * 8192), 16, 0, 0);
      if (wv < 4)
        __builtin_amdgcn_global_load_lds((const GU*)(wg + (size_t)(c + 1) * 4096),
                                         (LU*)(Ws + (cur ^ 1) * 4096 + wv * 1024),
                                         16, 0, 0);
    }

    const char* asb = As + cur * (NB * BK * 2);
    const char* wsb = Ws + cur * 4096;
    bf16x8 af[4], bfr[4];
    #pragma unroll
    for (int rt = 0; rt < 4; ++rt)
      af[rt] = *reinterpret_cast<const bf16x8*>(asb + aoff[rt]);
    #pragma unroll
    for (int ct = 0; ct < 4; ++ct)
      bfr[ct] = *reinterpret_cast<const bf16x8*>(wsb + boff[ct]);
    #pragma unroll
    for (int rt = 0; rt < 4; ++rt)
      #pragma unroll
      for (int ct = 0; ct < 4; ++ct)
        acc[rt][ct] = __builtin_amdgcn_mfma_f32_16x16x32_bf16(af[rt], bfr[ct],
                                                              acc[rt][ct], 0, 0, 0);
    __syncthreads();   // publishes buffers cur^1 (vmcnt+lgkm drained)
  }

  // ---- epilogue: acc IS cosine; e = exp(64*cos - 64); row-sum; replica atomic ----
  // C/D layout (16x16): col = lane&15 (class), row = quad*4 + reg
  int vmask[4];
  #pragma unroll
  for (int ct = 0; ct < 4; ++ct)
    vmask[ct] = (bc + ct * 16 + ra) < NC;
  float* gs = gsum + (size_t)(blockIdx.x & (REP - 1)) * NB;
  #pragma unroll
  for (int rt = 0; rt < 4; ++rt) {
    #pragma unroll
    for (int rg = 0; rg < 4; ++rg) {
      float es = 0.f;
      #pragma unroll
      for (int ct = 0; ct < 4; ++ct) {
        float e = __expf(fmaf(FSCALE, acc[rt][ct][rg], -FSCALE));
        es += vmask[ct] ? e : 0.f;
      }
      es += __shfl_xor(es, 1);
      es += __shfl_xor(es, 2);
      es += __shfl_xor(es, 4);
      es += __shfl_xor(es, 8);
      if (ra == 0) {
        atomicAdd(&gs[m_w + rt * 16 + quad * 4 + rg], es);
      }
    }
  }
}

// ---------------- 3-fallback) v4 kernel (fp32 W streaming) — used only if ws small ----
__global__ __launch_bounds__(512, 4) void gemm_lse_fb(
    const __bf16* __restrict__ xp, const float* __restrict__ w,
    float* __restrict__ gsum) {
  __shared__ __align__(16) char As[2 * NB * BK * 2];
  __shared__ __align__(16) char Ws[2 * CT * BK * 4];
  const int tid  = threadIdx.x;
  const int wv   = tid >> 6;
  const int lane = tid & 63;
  const int bc   = blockIdx.x * CT;
  const int p_w  = wv * 1024 + lane * 16;
  const int lbw  = SWZW(p_w);
  const int wrow = min(bc + (lbw >> 7), NC - 1);
  const char* wg = (const char*)w + (size_t)wrow * (ND * 4) + (lbw & 127);
  const char* ag = (const char*)xp + wv * 1024 + lane * 16;
  {
    char* la = As + wv * 1024;
    #pragma unroll
    for (int j = 0; j < 4; ++j)
      __builtin_amdgcn_global_load_lds((const GU*)(ag + j * 8192),
                                       (LU*)(la + j * 8192), 16, 0, 0);
    __builtin_amdgcn_global_load_lds((const GU*)wg, (LU*)(Ws + wv * 1024), 16, 0, 0);
  }
  const int m_w = wv * 64;
  const int ra = lane & 15;
  const int quad = lane >> 4;
  int aoff[4], woff[4];
  #pragma unroll
  for (int rt = 0; rt < 4; ++rt)
    aoff[rt] = SWZA((m_w + rt * 16 + ra) * 64 + quad * 16);
  #pragma unroll
  for (int ct = 0; ct < 4; ++ct)
    woff[ct] = SWZW((ct * 16 + ra) * 128 + quad * 32);
  f32x4 acc[4][4] = {};
  float wsq[4] = {0.f, 0.f, 0.f, 0.f};
  __syncthreads();
  for (int c = 0; c < NCHUNK; ++c) {
    const int cur = c & 1;
    if (c + 1 < NCHUNK) {
      const char* a1 = ag + (size_t)(c + 1) * (NB * BK * 2);
      char* la = As + (cur ^ 1) * (NB * BK * 2) + wv * 1024;
      #pragma unroll
      for (int j = 0; j < 4; ++j)
        __builtin_amdgcn_global_load_lds((const GU*)(a1 + j * 8192),
                                         (LU*)(la + j * 8192), 16, 0, 0);
      __builtin_amdgcn_global_load_lds((const GU*)(wg + (size_t)(c + 1) * 128),
                                       (LU*)(Ws + (cur ^ 1) * 8192 + wv * 1024),
                                       16, 0, 0);
    }
    const char* asb = As + cur * (NB * BK * 2);
    const char* wsb = Ws + cur * 8192;
    bf16x8 af[4];
    #pragma unroll
    for (int rt = 0; rt < 4; ++rt)
      af[rt] = *reinterpret_cast<const bf16x8*>(asb + aoff[rt]);
    #pragma unroll
    for (int ct = 0; ct < 4; ++ct) {
      float4 w0 = *reinterpret_cast<const float4*>(wsb + woff[ct]);
      float4 w1 = *reinterpret_cast<const float4*>(wsb + woff[ct] + 16);
      wsq[ct] += w0.x*w0.x + w0.y*w0.y + w0.z*w0.z + w0.w*w0.w
               + w1.x*w1.x + w1.y*w1.y + w1.z*w1.z + w1.w*w1.w;
      bf16x8 bfr;
      bfr[0] = (__bf16)w0.x; bfr[1] = (__bf16)w0.y;
      bfr[2] = (__bf16)w0.z; bfr[3] = (__bf16)w0.w;
      bfr[4] = (__bf16)w1.x; bfr[5] = (__bf16)w1.y;
      bfr[6] = (__bf16)w1.z; bfr[7] = (__bf16)w1.w;
      #pragma unroll
      for (int rt = 0; rt < 4; ++rt)
        acc[rt][ct] = __builtin_amdgcn_mfma_f32_16x16x32_bf16(af[rt], bfr,
                                                              acc[rt][ct], 0, 0, 0);
    }
    __syncthreads();
  }
  float rnw[4];
  int vmask[4];
  #pragma unroll
  for (int ct = 0; ct < 4; ++ct) {
    wsq[ct] += __shfl_xor(wsq[ct], 16);
    wsq[ct] += __shfl_xor(wsq[ct], 32);
    rnw[ct] = rsqrtf(fmaxf(wsq[ct], 1e-24f));
    vmask[ct] = (bc + ct * 16 + ra) < NC;
  }
  float* gs = gsum + (size_t)(blockIdx.x & (REP - 1)) * NB;
  #pragma unroll
  for (int rt = 0; rt < 4; ++rt) {
    #pragma unroll
    for (int rg = 0; rg < 4; ++rg) {
      float es = 0.f;
      #pragma unroll
      for (int ct = 0; ct < 4; ++ct) {
        float cosv = acc[rt][ct][rg] * rnw[ct];
        float e = __expf(fmaf(FSCALE, cosv, -FSCALE));
        es += vmask[ct] ? e : 0.f;
      }
      es += __shfl_xor(es, 1);
      es += __shfl_xor(es, 2);
      es += __shfl_xor(es, 4);
      es += __shfl_xor(es, 8);
      if (ra == 0) atomicAdd(&gs[m_w + rt * 16 + quad * 4 + rg], es);
    }
  }
}

// ---------------- 4) finalize (sums REP replicas) ----------------
__global__ void finalize_kernel(const float* __restrict__ gsum,
                                const float* __restrict__ cos_t,
                                const float* __restrict__ phi_t,
                                float* __restrict__ out) {
  const int b = threadIdx.x;   // 512
  float s = 0.f;
  #pragma unroll 8
  for (int r = 0; r < REP; ++r) s += gsum[r * NB + b];
  const float c = cos_t[b];
  const float p = phi_t[b];
  float corr = s - __expf(fmaf(FSCALE, c, -FSCALE))
                 + __expf(fmaf(FSCALE, p, -FSCALE));
  corr = fmaxf(corr, 1e-38f);
  float lb = FSCALE + logf(corr) - FSCALE * p;
  #pragma unroll
  for (int m = 1; m < 64; m <<= 1) lb += __shfl_xor(lb, m);
  __shared__ float pr[8];
  if ((b & 63) == 0) pr[b >> 6] = lb;
  __syncthreads();
  if (b == 0) {
    float tot = 0.f;
    #pragma unroll
    for (int j = 0; j < 8; ++j) tot += pr[j];
    out[0] = tot * (1.0f / NB);
  }
}

extern "C" void kernel_launch(void* const* d_in, const int* in_sizes, int n_in,
                              void* d_out, int out_size, void* d_ws, size_t ws_size,
                              hipStream_t stream) {
  const float* x  = (const float*)d_in[0];
  const float* w  = (const float*)d_in[1];
  const int* tgt  = (const int*)d_in[2];
  float* out      = (float*)d_out;

  // workspace: xp (512K) | gsum (128K) | cos_t/phi_t (4K) | [1MB:] wp (102.4M)
  __bf16* xp   = (__bf16*)d_ws;
  float* gsum  = (float*)((char*)d_ws + (size_t)NB * ND * 2);
  float* cos_t = gsum + (size_t)REP * NB;
  float* phi_t = cos_t + NB;
  const size_t WPOFF   = 1 << 20;
  const size_t WPBYTES = (size_t)NTILE * NCHUNK * 4096;   // 102,432,768
  __bf16* wp = (__bf16*)((char*)d_ws + WPOFF);

  hipMemsetAsync(gsum, 0, (size_t)REP * NB * sizeof(float), stream);
  pack_x_kernel<<<NB, 128, 0, stream>>>(x, xp);
  cosphi_kernel<<<NB, 64, 0, stream>>>(x, w, tgt, cos_t, phi_t);
  if (ws_size >= WPOFF + WPBYTES) {
    prep_w_kernel<<<NTILE, 512, 0, stream>>>(w, wp);
    gemm_lse_kernel<<<NTILE, 512, 0, stream>>>(xp, wp, gsum);
  } else {
    gemm_lse_fb<<<NTILE, 512, 0, stream>>>(xp, w, gsum);
  }
  finalize_kernel<<<1, 512, 0, stream>>>(gsum, cos_t, phi_t, out);
}

// Round 8
// 376.076 us; speedup vs baseline: 2.0912x; 1.0518x over previous
//
#include <hip/hip_runtime.h>
#include <math.h>

// ArcFaceLoss: B=512, D=512, C=100000, margin=0.5, scale=64
// v8 = v7 with prep_w FUSED into the gemm block prologue.
//   Rationale: prep->gemm dependency is block-diagonal (gemm block b needs only
//   W-tile b). Serial prep kernel (pure BW, ~0 compute) + serial gemm (latency
//   bound, ~12% pipes) each half-idle = ~185us; fused, a block's prep phase
//   overlaps the co-resident block's k-loop on the same CU.
//   Per block: read 64 fp32 rows (128KB, reg-stash, coalesced) -> sumsq ->
//   normalize+cvt bf16 -> store 64KB tile to global wp -> barrier -> v7 k-loop
//   glds-reads the tile back (same-XCD L2 hit). Layout identical to v7 (verified
//   absmax 0.0 in r7).

#define NB 512
#define ND 512
#define NC 100000
#define BK 32
#define NCHUNK 16          // ND / BK
#define CT 64              // classes per block
#define NTILE 1563         // ceil(NC / CT); padded classes = 100032
#define REP 64             // gsum replicas (atomic decongestion)
#define FSCALE 64.0f
#define C_COS_M 0.8775825618903728f
#define C_SIN_M 0.479425538604203f
#define C_TH  (-0.8775825618903728f)   // cos(pi - m)
#define C_MM  0.2397127693021015f      // sin(pi - m) * m

// Tile swizzle (proven v3-v7, conflicts==0): slot bits [5:4] ^= bits [8:7]
// (= row bits 1:2 for 64B rows). Involutive, preserves bits [3:0].
#define SWZA(b) ((b) ^ (((b) >> 3) & 48))
// fallback W swizzle (fp32 rows, 128 B)
#define SWZW(b) ((b) ^ (((b) >> 3) & 112))

typedef __bf16 bf16x8 __attribute__((ext_vector_type(8)));
typedef __bf16 bf16x4 __attribute__((ext_vector_type(4)));
typedef float  f32x4  __attribute__((ext_vector_type(4)));
typedef __attribute__((address_space(1))) unsigned int GU;
typedef __attribute__((address_space(3))) unsigned int LU;

// ---------------- 1) normalize + pack x (swizzled chunk-major, unchanged) ----------------
__global__ void pack_x_kernel(const float* __restrict__ x, __bf16* __restrict__ xp) {
  const int b = blockIdx.x;
  const int t = threadIdx.x;                   // 0..127
  float4 v = reinterpret_cast<const float4*>(x + (size_t)b * ND)[t];
  float ss = v.x*v.x + v.y*v.y + v.z*v.z + v.w*v.w;
  #pragma unroll
  for (int m = 1; m < 64; m <<= 1) ss += __shfl_xor(ss, m);
  __shared__ float sred[2];
  if ((t & 63) == 0) sred[t >> 6] = ss;
  __syncthreads();
  const float rn = rsqrtf(fmaxf(sred[0] + sred[1], 1e-24f));
  bf16x4 o;
  o[0] = (__bf16)(v.x * rn); o[1] = (__bf16)(v.y * rn);
  o[2] = (__bf16)(v.z * rn); o[3] = (__bf16)(v.w * rn);
  const int k = 4 * t;                         // element index 0..508
  const int chunk = k >> 5;
  const int lb = b * 64 + (k & 31) * 2;        // logical byte within 32KB chunk-block
  char* dst = (char*)xp + (size_t)chunk * (NB * BK * 2) + SWZA(lb);
  *reinterpret_cast<bf16x4*>(dst) = o;
}

// ---------------- 2) fp32-accurate target cosine + phi (unchanged) ----------------
__global__ void cosphi_kernel(const float* __restrict__ x, const float* __restrict__ w,
                              const int* __restrict__ tgt,
                              float* __restrict__ cos_t, float* __restrict__ phi_t) {
  const int b = blockIdx.x;
  const int lane = threadIdx.x;                // 0..63
  const int t = tgt[b];
  const float4* xr = reinterpret_cast<const float4*>(x + (size_t)b * ND);
  const float4* wr = reinterpret_cast<const float4*>(w + (size_t)t * ND);
  float dp = 0.f, xs = 0.f, ws = 0.f;
  #pragma unroll
  for (int j = 0; j < 2; ++j) {
    float4 xv = xr[lane * 2 + j];
    float4 wv = wr[lane * 2 + j];
    dp += xv.x*wv.x + xv.y*wv.y + xv.z*wv.z + xv.w*wv.w;
    xs += xv.x*xv.x + xv.y*xv.y + xv.z*xv.z + xv.w*xv.w;
    ws += wv.x*wv.x + wv.y*wv.y + wv.z*wv.z + wv.w*wv.w;
  }
  #pragma unroll
  for (int m = 1; m < 64; m <<= 1) {
    dp += __shfl_xor(dp, m);
    xs += __shfl_xor(xs, m);
    ws += __shfl_xor(ws, m);
  }
  if (lane == 0) {
    float c = dp * rsqrtf(fmaxf(xs, 1e-24f)) * rsqrtf(fmaxf(ws, 1e-24f));
    c = fminf(fmaxf(c, -1.f), 1.f);
    float s = sqrtf(fmaxf(1.f - c * c, 0.f));
    float phi = c * C_COS_M - s * C_SIN_M;
    phi = (c > C_TH) ? phi : (c - C_MM);
    cos_t[b] = c;
    phi_t[b] = phi;
  }
}

// ---------------- 3) fused prep + GEMM + partial sum-exp (v8) ----------------
// 512 threads = 8 waves. Wave wv owns rows [64wv, 64wv+64) x 64 classes (4x4 frags).
// Prologue: issue A0 glds; prep own W tile (fp32 read -> norm -> bf16 -> global wp);
// barrier; stage W0; barrier. k-loop identical to v7:
// glds A(c+1) (4/wave) + glds W(c+1) (1, waves 0-3) -> 4+4 ds_read_b128
// -> 16 MFMA -> barrier. MFMA output is cosine directly.
__global__ __launch_bounds__(512, 4) void gemm_lse_kernel(
    const __bf16* __restrict__ xp, const float* __restrict__ w,
    __bf16* __restrict__ wp, float* __restrict__ gsum) {
  __shared__ __align__(16) char As[2 * NB * BK * 2];   // 2 x 32 KB (swizzled)
  __shared__ __align__(16) char Ws[2 * CT * BK * 2];   // 2 x 4 KB  (swizzled)

  const int tid  = threadIdx.x;
  const int wv   = tid >> 6;          // 0..7
  const int lane = tid & 63;
  const int bc   = blockIdx.x * CT;

  const char* ag = (const char*)xp + wv * 1024 + lane * 16;
  char* wtile = (char*)wp + (size_t)blockIdx.x * (NCHUNK * 4096);
  const char* wg = wtile + wv * 1024 + lane * 16;      // glds source (waves 0-3)

  // ---- issue A chunk-0 glds first (fills LDS during the prep phase) ----
  {
    char* la = As + wv * 1024;
    #pragma unroll
    for (int j = 0; j < 4; ++j)
      __builtin_amdgcn_global_load_lds((const GU*)(ag + j * 8192),
                                       (LU*)(la + j * 8192), 16, 0, 0);
  }

  // ---- prep phase: normalize own 64-row W tile -> bf16 -> global wp ----
  // (v7 prep_w body, verbatim layout: wp + tile*65536 + chunk*4096
  //  + SWZA(lrow*64 + (k&31)*2); verified absmax 0.0 in r7)
  {
    const int row  = bc + (tid >> 3);
    const int part = tid & 7;
    const int srow = min(row, NC - 1);
    const float4* src = reinterpret_cast<const float4*>(w + (size_t)srow * ND);
    float4 v[16];
    float ss = 0.f;
    #pragma unroll
    for (int j = 0; j < 16; ++j) {
      v[j] = src[j * 8 + part];                // element k = 32j+4*part -> chunk j
      ss += v[j].x*v[j].x + v[j].y*v[j].y + v[j].z*v[j].z + v[j].w*v[j].w;
    }
    ss += __shfl_xor(ss, 1);
    ss += __shfl_xor(ss, 2);
    ss += __shfl_xor(ss, 4);
    float rn = rsqrtf(fmaxf(ss, 1e-24f));
    if (row >= NC) rn = 0.f;                   // zero pad rows
    const int lrow = tid >> 3;                 // row & 63
    const int slot = SWZA(lrow * 64 + part * 8);
    #pragma unroll
    for (int j = 0; j < 16; ++j) {
      bf16x4 o;
      o[0] = (__bf16)(v[j].x * rn); o[1] = (__bf16)(v[j].y * rn);
      o[2] = (__bf16)(v[j].z * rn); o[3] = (__bf16)(v[j].w * rn);
      *reinterpret_cast<bf16x4*>(wtile + j * 4096 + slot) = o;
    }
  }
  __syncthreads();   // drains each wave's wp stores (to L2) + A0 glds

  // ---- stage W chunk-0 from the tile just written (same-XCD L2 hit) ----
  if (wv < 4)
    __builtin_amdgcn_global_load_lds((const GU*)wg, (LU*)(Ws + wv * 1024), 16, 0, 0);
  __syncthreads();   // W0 ready

  // ---- fragment offsets (loop-invariant, swizzled) ----
  const int m_w  = wv * 64;
  const int ra   = lane & 15;
  const int quad = lane >> 4;
  int aoff[4], boff[4];
  #pragma unroll
  for (int rt = 0; rt < 4; ++rt)
    aoff[rt] = SWZA((m_w + rt * 16 + ra) * 64 + quad * 16);
  #pragma unroll
  for (int ct = 0; ct < 4; ++ct)
    boff[ct] = SWZA((ct * 16 + ra) * 64 + quad * 16);

  f32x4 acc[4][4] = {};

  for (int c = 0; c < NCHUNK; ++c) {
    const int cur = c & 1;
    if (c + 1 < NCHUNK) {
      const char* a1 = ag + (size_t)(c + 1) * (NB * BK * 2);
      char* la = As + (cur ^ 1) * (NB * BK * 2) + wv * 1024;
      #pragma unroll
      for (int j = 0; j < 4; ++j)
        __builtin_amdgcn_global_load_lds((const GU*)(a1 + j * 8192),
                                         (LU*)(la + j * 8192), 16, 0, 0);
      if (wv < 4)
        __builtin_amdgcn_global_load_lds((const GU*)(wg + (size_t)(c + 1) * 4096),
                                         (LU*)(Ws + (cur ^ 1) * 4096 + wv * 1024),
                                         16, 0, 0);
    }

    const char* asb = As + cur * (NB * BK * 2);
    const char* wsb = Ws + cur * 4096;
    bf16x8 af[4], bfr[4];
    #pragma unroll
    for (int rt = 0; rt < 4; ++rt)
      af[rt] = *reinterpret_cast<const bf16x8*>(asb + aoff[rt]);
    #pragma unroll
    for (int ct = 0; ct < 4; ++ct)
      bfr[ct] = *reinterpret_cast<const bf16x8*>(wsb + boff[ct]);
    #pragma unroll
    for (int rt = 0; rt < 4; ++rt)
      #pragma unroll
      for (int ct = 0; ct < 4; ++ct)
        acc[rt][ct] = __builtin_amdgcn_mfma_f32_16x16x32_bf16(af[rt], bfr[ct],
                                                              acc[rt][ct], 0, 0, 0);
    __syncthreads();   // publishes buffers cur^1 (vmcnt+lgkm drained)
  }

  // ---- epilogue: acc IS cosine; e = exp(64*cos - 64); row-sum; replica atomic ----
  // C/D layout (16x16): col = lane&15 (class), row = quad*4 + reg
  int vmask[4];
  #pragma unroll
  for (int ct = 0; ct < 4; ++ct)
    vmask[ct] = (bc + ct * 16 + ra) < NC;
  float* gs = gsum + (size_t)(blockIdx.x & (REP - 1)) * NB;
  #pragma unroll
  for (int rt = 0; rt < 4; ++rt) {
    #pragma unroll
    for (int rg = 0; rg < 4; ++rg) {
      float es = 0.f;
      #pragma unroll
      for (int ct = 0; ct < 4; ++ct) {
        float e = __expf(fmaf(FSCALE, acc[rt][ct][rg], -FSCALE));
        es += vmask[ct] ? e : 0.f;
      }
      es += __shfl_xor(es, 1);
      es += __shfl_xor(es, 2);
      es += __shfl_xor(es, 4);
      es += __shfl_xor(es, 8);
      if (ra == 0) {
        atomicAdd(&gs[m_w + rt * 16 + quad * 4 + rg], es);
      }
    }
  }
}

// ---------------- 3-fallback) v4 kernel (fp32 W streaming) — used only if ws small ----
__global__ __launch_bounds__(512, 4) void gemm_lse_fb(
    const __bf16* __restrict__ xp, const float* __restrict__ w,
    float* __restrict__ gsum) {
  __shared__ __align__(16) char As[2 * NB * BK * 2];
  __shared__ __align__(16) char Ws[2 * CT * BK * 4];
  const int tid  = threadIdx.x;
  const int wv   = tid >> 6;
  const int lane = tid & 63;
  const int bc   = blockIdx.x * CT;
  const int p_w  = wv * 1024 + lane * 16;
  const int lbw  = SWZW(p_w);
  const int wrow = min(bc + (lbw >> 7), NC - 1);
  const char* wg = (const char*)w + (size_t)wrow * (ND * 4) + (lbw & 127);
  const char* ag = (const char*)xp + wv * 1024 + lane * 16;
  {
    char* la = As + wv * 1024;
    #pragma unroll
    for (int j = 0; j < 4; ++j)
      __builtin_amdgcn_global_load_lds((const GU*)(ag + j * 8192),
                                       (LU*)(la + j * 8192), 16, 0, 0);
    __builtin_amdgcn_global_load_lds((const GU*)wg, (LU*)(Ws + wv * 1024), 16, 0, 0);
  }
  const int m_w = wv * 64;
  const int ra = lane & 15;
  const int quad = lane >> 4;
  int aoff[4], woff[4];
  #pragma unroll
  for (int rt = 0; rt < 4; ++rt)
    aoff[rt] = SWZA((m_w + rt * 16 + ra) * 64 + quad * 16);
  #pragma unroll
  for (int ct = 0; ct < 4; ++ct)
    woff[ct] = SWZW((ct * 16 + ra) * 128 + quad * 32);
  f32x4 acc[4][4] = {};
  float wsq[4] = {0.f, 0.f, 0.f, 0.f};
  __syncthreads();
  for (int c = 0; c < NCHUNK; ++c) {
    const int cur = c & 1;
    if (c + 1 < NCHUNK) {
      const char* a1 = ag + (size_t)(c + 1) * (NB * BK * 2);
      char* la = As + (cur ^ 1) * (NB * BK * 2) + wv * 1024;
      #pragma unroll
      for (int j = 0; j < 4; ++j)
        __builtin_amdgcn_global_load_lds((const GU*)(a1 + j * 8192),
                                         (LU*)(la + j * 8192), 16, 0, 0);
      __builtin_amdgcn_global_load_lds((const GU*)(wg + (size_t)(c + 1) * 128),
                                       (LU*)(Ws + (cur ^ 1) * 8192 + wv * 1024),
                                       16, 0, 0);
    }
    const char* asb = As + cur * (NB * BK * 2);
    const char* wsb = Ws + cur * 8192;
    bf16x8 af[4];
    #pragma unroll
    for (int rt = 0; rt < 4; ++rt)
      af[rt] = *reinterpret_cast<const bf16x8*>(asb + aoff[rt]);
    #pragma unroll
    for (int ct = 0; ct < 4; ++ct) {
      float4 w0 = *reinterpret_cast<const float4*>(wsb + woff[ct]);
      float4 w1 = *reinterpret_cast<const float4*>(wsb + woff[ct] + 16);
      wsq[ct] += w0.x*w0.x + w0.y*w0.y + w0.z*w0.z + w0.w*w0.w
               + w1.x*w1.x + w1.y*w1.y + w1.z*w1.z + w1.w*w1.w;
      bf16x8 bfr;
      bfr[0] = (__bf16)w0.x; bfr[1] = (__bf16)w0.y;
      bfr[2] = (__bf16)w0.z; bfr[3] = (__bf16)w0.w;
      bfr[4] = (__bf16)w1.x; bfr[5] = (__bf16)w1.y;
      bfr[6] = (__bf16)w1.z; bfr[7] = (__bf16)w1.w;
      #pragma unroll
      for (int rt = 0; rt < 4; ++rt)
        acc[rt][ct] = __builtin_amdgcn_mfma_f32_16x16x32_bf16(af[rt], bfr,
                                                              acc[rt][ct], 0, 0, 0);
    }
    __syncthreads();
  }
  float rnw[4];
  int vmask[4];
  #pragma unroll
  for (int ct = 0; ct < 4; ++ct) {
    wsq[ct] += __shfl_xor(wsq[ct], 16);
    wsq[ct] += __shfl_xor(wsq[ct], 32);
    rnw[ct] = rsqrtf(fmaxf(wsq[ct], 1e-24f));
    vmask[ct] = (bc + ct * 16 + ra) < NC;
  }
  float* gs = gsum + (size_t)(blockIdx.x & (REP - 1)) * NB;
  #pragma unroll
  for (int rt = 0; rt < 4; ++rt) {
    #pragma unroll
    for (int rg = 0; rg < 4; ++rg) {
      float es = 0.f;
      #pragma unroll
      for (int ct = 0; ct < 4; ++ct) {
        float cosv = acc[rt][ct][rg] * rnw[ct];
        float e = __expf(fmaf(FSCALE, cosv, -FSCALE));
        es += vmask[ct] ? e : 0.f;
      }
      es += __shfl_xor(es, 1);
      es += __shfl_xor(es, 2);
      es += __shfl_xor(es, 4);
      es += __shfl_xor(es, 8);
      if (ra == 0) atomicAdd(&gs[m_w + rt * 16 + quad * 4 + rg], es);
    }
  }
}

// ---------------- 4) finalize (sums REP replicas) ----------------
__global__ void finalize_kernel(const float* __restrict__ gsum,
                                const float* __restrict__ cos_t,
                                const float* __restrict__ phi_t,
                                float* __restrict__ out) {
  const int b = threadIdx.x;   // 512
  float s = 0.f;
  #pragma unroll 8
  for (int r = 0; r < REP; ++r) s += gsum[r * NB + b];
  const float c = cos_t[b];
  const float p = phi_t[b];
  float corr = s - __expf(fmaf(FSCALE, c, -FSCALE))
                 + __expf(fmaf(FSCALE, p, -FSCALE));
  corr = fmaxf(corr, 1e-38f);
  float lb = FSCALE + logf(corr) - FSCALE * p;
  #pragma unroll
  for (int m = 1; m < 64; m <<= 1) lb += __shfl_xor(lb, m);
  __shared__ float pr[8];
  if ((b & 63) == 0) pr[b >> 6] = lb;
  __syncthreads();
  if (b == 0) {
    float tot = 0.f;
    #pragma unroll
    for (int j = 0; j < 8; ++j) tot += pr[j];
    out[0] = tot * (1.0f / NB);
  }
}

extern "C" void kernel_launch(void* const* d_in, const int* in_sizes, int n_in,
                              void* d_out, int out_size, void* d_ws, size_t ws_size,
                              hipStream_t stream) {
  const float* x  = (const float*)d_in[0];
  const float* w  = (const float*)d_in[1];
  const int* tgt  = (const int*)d_in[2];
  float* out      = (float*)d_out;

  // workspace: xp (512K) | gsum (128K) | cos_t/phi_t (4K) | [1MB:] wp (102.4M)
  __bf16* xp   = (__bf16*)d_ws;
  float* gsum  = (float*)((char*)d_ws + (size_t)NB * ND * 2);
  float* cos_t = gsum + (size_t)REP * NB;
  float* phi_t = cos_t + NB;
  const size_t WPOFF   = 1 << 20;
  const size_t WPBYTES = (size_t)NTILE * NCHUNK * 4096;   // 102,432,768
  __bf16* wp = (__bf16*)((char*)d_ws + WPOFF);

  hipMemsetAsync(gsum, 0, (size_t)REP * NB * sizeof(float), stream);
  pack_x_kernel<<<NB, 128, 0, stream>>>(x, xp);
  cosphi_kernel<<<NB, 64, 0, stream>>>(x, w, tgt, cos_t, phi_t);
  if (ws_size >= WPOFF + WPBYTES) {
    gemm_lse_kernel<<<NTILE, 512, 0, stream>>>(xp, w, wp, gsum);
  } else {
    gemm_lse_fb<<<NTILE, 512, 0, stream>>>(xp, w, gsum);
  }
  finalize_kernel<<<1, 512, 0, stream>>>(gsum, cos_t, phi_t, out);
}

// Round 9
// 363.259 us; speedup vs baseline: 2.1650x; 1.0353x over previous
//
#include <hip/hip_runtime.h>
#include <math.h>

// ArcFaceLoss: B=512, D=512, C=100000, margin=0.5, scale=64
// v9 = v8 (fused prep+gemm, proven absmax 0.0) with the k-loop sync discipline
//   upgraded from __syncthreads (vmcnt(0) drain of the JUST-ISSUED prefetch,
//   ~4300 cy/chunk) to counted s_waitcnt vmcnt(N) + raw s_barrier (T3/T4):
//   wait only for the chunk being read (issued one full iteration ago); the
//   just-issued chunk's loads stay in flight across both barriers.
//   vmcnt N per wave role: waves 0-3 issue 4 A + 1 W = 5/chunk; waves 4-7 = 4.

#define NB 512
#define ND 512
#define NC 100000
#define BK 32
#define NCHUNK 16          // ND / BK
#define CT 64              // classes per block
#define NTILE 1563         // ceil(NC / CT); padded classes = 100032
#define REP 64             // gsum replicas (atomic decongestion)
#define FSCALE 64.0f
#define C_COS_M 0.8775825618903728f
#define C_SIN_M 0.479425538604203f
#define C_TH  (-0.8775825618903728f)   // cos(pi - m)
#define C_MM  0.2397127693021015f      // sin(pi - m) * m

// Tile swizzle (proven v3-v8, conflicts==0): slot bits [5:4] ^= bits [8:7].
#define SWZA(b) ((b) ^ (((b) >> 3) & 48))
// fallback W swizzle (fp32 rows, 128 B)
#define SWZW(b) ((b) ^ (((b) >> 3) & 112))

typedef __bf16 bf16x8 __attribute__((ext_vector_type(8)));
typedef __bf16 bf16x4 __attribute__((ext_vector_type(4)));
typedef float  f32x4  __attribute__((ext_vector_type(4)));
typedef __attribute__((address_space(1))) unsigned int GU;
typedef __attribute__((address_space(3))) unsigned int LU;

// ---------------- 1) normalize + pack x (swizzled chunk-major, unchanged) ----------------
__global__ void pack_x_kernel(const float* __restrict__ x, __bf16* __restrict__ xp) {
  const int b = blockIdx.x;
  const int t = threadIdx.x;                   // 0..127
  float4 v = reinterpret_cast<const float4*>(x + (size_t)b * ND)[t];
  float ss = v.x*v.x + v.y*v.y + v.z*v.z + v.w*v.w;
  #pragma unroll
  for (int m = 1; m < 64; m <<= 1) ss += __shfl_xor(ss, m);
  __shared__ float sred[2];
  if ((t & 63) == 0) sred[t >> 6] = ss;
  __syncthreads();
  const float rn = rsqrtf(fmaxf(sred[0] + sred[1], 1e-24f));
  bf16x4 o;
  o[0] = (__bf16)(v.x * rn); o[1] = (__bf16)(v.y * rn);
  o[2] = (__bf16)(v.z * rn); o[3] = (__bf16)(v.w * rn);
  const int k = 4 * t;                         // element index 0..508
  const int chunk = k >> 5;
  const int lb = b * 64 + (k & 31) * 2;        // logical byte within 32KB chunk-block
  char* dst = (char*)xp + (size_t)chunk * (NB * BK * 2) + SWZA(lb);
  *reinterpret_cast<bf16x4*>(dst) = o;
}

// ---------------- 2) fp32-accurate target cosine + phi (unchanged) ----------------
__global__ void cosphi_kernel(const float* __restrict__ x, const float* __restrict__ w,
                              const int* __restrict__ tgt,
                              float* __restrict__ cos_t, float* __restrict__ phi_t) {
  const int b = blockIdx.x;
  const int lane = threadIdx.x;                // 0..63
  const int t = tgt[b];
  const float4* xr = reinterpret_cast<const float4*>(x + (size_t)b * ND);
  const float4* wr = reinterpret_cast<const float4*>(w + (size_t)t * ND);
  float dp = 0.f, xs = 0.f, ws = 0.f;
  #pragma unroll
  for (int j = 0; j < 2; ++j) {
    float4 xv = xr[lane * 2 + j];
    float4 wv = wr[lane * 2 + j];
    dp += xv.x*wv.x + xv.y*wv.y + xv.z*wv.z + xv.w*wv.w;
    xs += xv.x*xv.x + xv.y*xv.y + xv.z*xv.z + xv.w*xv.w;
    ws += wv.x*wv.x + wv.y*wv.y + wv.z*wv.z + wv.w*wv.w;
  }
  #pragma unroll
  for (int m = 1; m < 64; m <<= 1) {
    dp += __shfl_xor(dp, m);
    xs += __shfl_xor(xs, m);
    ws += __shfl_xor(ws, m);
  }
  if (lane == 0) {
    float c = dp * rsqrtf(fmaxf(xs, 1e-24f)) * rsqrtf(fmaxf(ws, 1e-24f));
    c = fminf(fmaxf(c, -1.f), 1.f);
    float s = sqrtf(fmaxf(1.f - c * c, 0.f));
    float phi = c * C_COS_M - s * C_SIN_M;
    phi = (c > C_TH) ? phi : (c - C_MM);
    cos_t[b] = c;
    phi_t[b] = phi;
  }
}

// ---------------- 3) fused prep + GEMM + partial sum-exp (v9) ----------------
__global__ __launch_bounds__(512, 4) void gemm_lse_kernel(
    const __bf16* __restrict__ xp, const float* __restrict__ w,
    __bf16* __restrict__ wp, float* __restrict__ gsum) {
  __shared__ __align__(16) char As[2 * NB * BK * 2];   // 2 x 32 KB (swizzled)
  __shared__ __align__(16) char Ws[2 * CT * BK * 2];   // 2 x 4 KB  (swizzled)

  const int tid  = threadIdx.x;
  const int wv   = tid >> 6;          // 0..7
  const int lane = tid & 63;
  const int bc   = blockIdx.x * CT;

  const char* ag = (const char*)xp + wv * 1024 + lane * 16;
  char* wtile = (char*)wp + (size_t)blockIdx.x * (NCHUNK * 4096);
  const char* wg = wtile + wv * 1024 + lane * 16;      // glds source (waves 0-3)

  // ---- issue A chunk-0 glds first (fills LDS during the prep phase) ----
  {
    char* la = As + wv * 1024;
    #pragma unroll
    for (int j = 0; j < 4; ++j)
      __builtin_amdgcn_global_load_lds((const GU*)(ag + j * 8192),
                                       (LU*)(la + j * 8192), 16, 0, 0);
  }

  // ---- prep phase: normalize own 64-row W tile -> bf16 -> global wp ----
  // (v7/v8 layout, verified absmax 0.0)
  {
    const int row  = bc + (tid >> 3);
    const int part = tid & 7;
    const int srow = min(row, NC - 1);
    const float4* src = reinterpret_cast<const float4*>(w + (size_t)srow * ND);
    float4 v[16];
    float ss = 0.f;
    #pragma unroll
    for (int j = 0; j < 16; ++j) {
      v[j] = src[j * 8 + part];                // element k = 32j+4*part -> chunk j
      ss += v[j].x*v[j].x + v[j].y*v[j].y + v[j].z*v[j].z + v[j].w*v[j].w;
    }
    ss += __shfl_xor(ss, 1);
    ss += __shfl_xor(ss, 2);
    ss += __shfl_xor(ss, 4);
    float rn = rsqrtf(fmaxf(ss, 1e-24f));
    if (row >= NC) rn = 0.f;                   // zero pad rows
    const int lrow = tid >> 3;                 // row & 63
    const int slot = SWZA(lrow * 64 + part * 8);
    #pragma unroll
    for (int j = 0; j < 16; ++j) {
      bf16x4 o;
      o[0] = (__bf16)(v[j].x * rn); o[1] = (__bf16)(v[j].y * rn);
      o[2] = (__bf16)(v[j].z * rn); o[3] = (__bf16)(v[j].w * rn);
      *reinterpret_cast<bf16x4*>(wtile + j * 4096 + slot) = o;
    }
  }
  __syncthreads();   // FULL drain (once): wp stores visible in L2, A0 glds landed

  // ---- stage W chunk-0 (reads the tile just written: same-XCD L2 hit) ----
  // No extra sync: loop iter-0's counted wait + barrier covers it.
  if (wv < 4)
    __builtin_amdgcn_global_load_lds((const GU*)wg, (LU*)(Ws + wv * 1024), 16, 0, 0);

  // ---- fragment offsets (loop-invariant, swizzled) ----
  const int m_w  = wv * 64;
  const int ra   = lane & 15;
  const int quad = lane >> 4;
  int aoff[4], boff[4];
  #pragma unroll
  for (int rt = 0; rt < 4; ++rt)
    aoff[rt] = SWZA((m_w + rt * 16 + ra) * 64 + quad * 16);
  #pragma unroll
  for (int ct = 0; ct < 4; ++ct)
    boff[ct] = SWZA((ct * 16 + ra) * 64 + quad * 16);

  f32x4 acc[4][4] = {};

  // ---- k-loop: counted-vmcnt 2-phase (T3/T4). Per iter c:
  //   issue stage(c+1) -> buf[cur^1]          (stays in flight across barriers)
  //   s_waitcnt vmcnt(5|4)                    (= stage(c) fully in LDS, mine)
  //   s_barrier                               (everyone's chunk-c in LDS)
  //   ds_read buf[cur] + 16 MFMA              (compiler-managed lgkmcnt)
  //   s_barrier                               (readers done -> buf reusable)
  for (int c = 0; c < NCHUNK; ++c) {
    const int cur = c & 1;
    if (c + 1 < NCHUNK) {
      const char* a1 = ag + (size_t)(c + 1) * (NB * BK * 2);
      char* la = As + (cur ^ 1) * (NB * BK * 2) + wv * 1024;
      #pragma unroll
      for (int j = 0; j < 4; ++j)
        __builtin_amdgcn_global_load_lds((const GU*)(a1 + j * 8192),
                                         (LU*)(la + j * 8192), 16, 0, 0);
      if (wv < 4) {
        __builtin_amdgcn_global_load_lds((const GU*)(wg + (size_t)(c + 1) * 4096),
                                         (LU*)(Ws + (cur ^ 1) * 4096 + wv * 1024),
                                         16, 0, 0);
        asm volatile("s_waitcnt vmcnt(5)" ::: "memory");
      } else {
        asm volatile("s_waitcnt vmcnt(4)" ::: "memory");
      }
    } else {
      asm volatile("s_waitcnt vmcnt(0)" ::: "memory");
    }
    __builtin_amdgcn_sched_barrier(0);
    __builtin_amdgcn_s_barrier();              // chunk c published
    __builtin_amdgcn_sched_barrier(0);

    const char* asb = As + cur * (NB * BK * 2);
    const char* wsb = Ws + cur * 4096;
    bf16x8 af[4], bfr[4];
    #pragma unroll
    for (int rt = 0; rt < 4; ++rt)
      af[rt] = *reinterpret_cast<const bf16x8*>(asb + aoff[rt]);
    #pragma unroll
    for (int ct = 0; ct < 4; ++ct)
      bfr[ct] = *reinterpret_cast<const bf16x8*>(wsb + boff[ct]);
    #pragma unroll
    for (int rt = 0; rt < 4; ++rt)
      #pragma unroll
      for (int ct = 0; ct < 4; ++ct)
        acc[rt][ct] = __builtin_amdgcn_mfma_f32_16x16x32_bf16(af[rt], bfr[ct],
                                                              acc[rt][ct], 0, 0, 0);
    __builtin_amdgcn_sched_barrier(0);
    __builtin_amdgcn_s_barrier();              // buf[cur] free for overwrite
    __builtin_amdgcn_sched_barrier(0);
  }

  // ---- epilogue: acc IS cosine; e = exp(64*cos - 64); row-sum; replica atomic ----
  // C/D layout (16x16): col = lane&15 (class), row = quad*4 + reg
  int vmask[4];
  #pragma unroll
  for (int ct = 0; ct < 4; ++ct)
    vmask[ct] = (bc + ct * 16 + ra) < NC;
  float* gs = gsum + (size_t)(blockIdx.x & (REP - 1)) * NB;
  #pragma unroll
  for (int rt = 0; rt < 4; ++rt) {
    #pragma unroll
    for (int rg = 0; rg < 4; ++rg) {
      float es = 0.f;
      #pragma unroll
      for (int ct = 0; ct < 4; ++ct) {
        float e = __expf(fmaf(FSCALE, acc[rt][ct][rg], -FSCALE));
        es += vmask[ct] ? e : 0.f;
      }
      es += __shfl_xor(es, 1);
      es += __shfl_xor(es, 2);
      es += __shfl_xor(es, 4);
      es += __shfl_xor(es, 8);
      if (ra == 0) {
        atomicAdd(&gs[m_w + rt * 16 + quad * 4 + rg], es);
      }
    }
  }
}

// ---------------- 3-fallback) v4 kernel (fp32 W streaming) — used only if ws small ----
__global__ __launch_bounds__(512, 4) void gemm_lse_fb(
    const __bf16* __restrict__ xp, const float* __restrict__ w,
    float* __restrict__ gsum) {
  __shared__ __align__(16) char As[2 * NB * BK * 2];
  __shared__ __align__(16) char Ws[2 * CT * BK * 4];
  const int tid  = threadIdx.x;
  const int wv   = tid >> 6;
  const int lane = tid & 63;
  const int bc   = blockIdx.x * CT;
  const int p_w  = wv * 1024 + lane * 16;
  const int lbw  = SWZW(p_w);
  const int wrow = min(bc + (lbw >> 7), NC - 1);
  const char* wg = (const char*)w + (size_t)wrow * (ND * 4) + (lbw & 127);
  const char* ag = (const char*)xp + wv * 1024 + lane * 16;
  {
    char* la = As + wv * 1024;
    #pragma unroll
    for (int j = 0; j < 4; ++j)
      __builtin_amdgcn_global_load_lds((const GU*)(ag + j * 8192),
                                       (LU*)(la + j * 8192), 16, 0, 0);
    __builtin_amdgcn_global_load_lds((const GU*)wg, (LU*)(Ws + wv * 1024), 16, 0, 0);
  }
  const int m_w = wv * 64;
  const int ra = lane & 15;
  const int quad = lane >> 4;
  int aoff[4], woff[4];
  #pragma unroll
  for (int rt = 0; rt < 4; ++rt)
    aoff[rt] = SWZA((m_w + rt * 16 + ra) * 64 + quad * 16);
  #pragma unroll
  for (int ct = 0; ct < 4; ++ct)
    woff[ct] = SWZW((ct * 16 + ra) * 128 + quad * 32);
  f32x4 acc[4][4] = {};
  float wsq[4] = {0.f, 0.f, 0.f, 0.f};
  __syncthreads();
  for (int c = 0; c < NCHUNK; ++c) {
    const int cur = c & 1;
    if (c + 1 < NCHUNK) {
      const char* a1 = ag + (size_t)(c + 1) * (NB * BK * 2);
      char* la = As + (cur ^ 1) * (NB * BK * 2) + wv * 1024;
      #pragma unroll
      for (int j = 0; j < 4; ++j)
        __builtin_amdgcn_global_load_lds((const GU*)(a1 + j * 8192),
                                         (LU*)(la + j * 8192), 16, 0, 0);
      __builtin_amdgcn_global_load_lds((const GU*)(wg + (size_t)(c + 1) * 128),
                                       (LU*)(Ws + (cur ^ 1) * 8192 + wv * 1024),
                                       16, 0, 0);
    }
    const char* asb = As + cur * (NB * BK * 2);
    const char* wsb = Ws + cur * 8192;
    bf16x8 af[4];
    #pragma unroll
    for (int rt = 0; rt < 4; ++rt)
      af[rt] = *reinterpret_cast<const bf16x8*>(asb + aoff[rt]);
    #pragma unroll
    for (int ct = 0; ct < 4; ++ct) {
      float4 w0 = *reinterpret_cast<const float4*>(wsb + woff[ct]);
      float4 w1 = *reinterpret_cast<const float4*>(wsb + woff[ct] + 16);
      wsq[ct] += w0.x*w0.x + w0.y*w0.y + w0.z*w0.z + w0.w*w0.w
               + w1.x*w1.x + w1.y*w1.y + w1.z*w1.z + w1.w*w1.w;
      bf16x8 bfr;
      bfr[0] = (__bf16)w0.x; bfr[1] = (__bf16)w0.y;
      bfr[2] = (__bf16)w0.z; bfr[3] = (__bf16)w0.w;
      bfr[4] = (__bf16)w1.x; bfr[5] = (__bf16)w1.y;
      bfr[6] = (__bf16)w1.z; bfr[7] = (__bf16)w1.w;
      #pragma unroll
      for (int rt = 0; rt < 4; ++rt)
        acc[rt][ct] = __builtin_amdgcn_mfma_f32_16x16x32_bf16(af[rt], bfr,
                                                              acc[rt][ct], 0, 0, 0);
    }
    __syncthreads();
  }
  float rnw[4];
  int vmask[4];
  #pragma unroll
  for (int ct = 0; ct < 4; ++ct) {
    wsq[ct] += __shfl_xor(wsq[ct], 16);
    wsq[ct] += __shfl_xor(wsq[ct], 32);
    rnw[ct] = rsqrtf(fmaxf(wsq[ct], 1e-24f));
    vmask[ct] = (bc + ct * 16 + ra) < NC;
  }
  float* gs = gsum + (size_t)(blockIdx.x & (REP - 1)) * NB;
  #pragma unroll
  for (int rt = 0; rt < 4; ++rt) {
    #pragma unroll
    for (int rg = 0; rg < 4; ++rg) {
      float es = 0.f;
      #pragma unroll
      for (int ct = 0; ct < 4; ++ct) {
        float cosv = acc[rt][ct][rg] * rnw[ct];
        float e = __expf(fmaf(FSCALE, cosv, -FSCALE));
        es += vmask[ct] ? e : 0.f;
      }
      es += __shfl_xor(es, 1);
      es += __shfl_xor(es, 2);
      es += __shfl_xor(es, 4);
      es += __shfl_xor(es, 8);
      if (ra == 0) atomicAdd(&gs[m_w + rt * 16 + quad * 4 + rg], es);
    }
  }
}

// ---------------- 4) finalize (sums REP replicas) ----------------
__global__ void finalize_kernel(const float* __restrict__ gsum,
                                const float* __restrict__ cos_t,
                                const float* __restrict__ phi_t,
                                float* __restrict__ out) {
  const int b = threadIdx.x;   // 512
  float s = 0.f;
  #pragma unroll 8
  for (int r = 0; r < REP; ++r) s += gsum[r * NB + b];
  const float c = cos_t[b];
  const float p = phi_t[b];
  float corr = s - __expf(fmaf(FSCALE, c, -FSCALE))
                 + __expf(fmaf(FSCALE, p, -FSCALE));
  corr = fmaxf(corr, 1e-38f);
  float lb = FSCALE + logf(corr) - FSCALE * p;
  #pragma unroll
  for (int m = 1; m < 64; m <<= 1) lb += __shfl_xor(lb, m);
  __shared__ float pr[8];
  if ((b & 63) == 0) pr[b >> 6] = lb;
  __syncthreads();
  if (b == 0) {
    float tot = 0.f;
    #pragma unroll
    for (int j = 0; j < 8; ++j) tot += pr[j];
    out[0] = tot * (1.0f / NB);
  }
}

extern "C" void kernel_launch(void* const* d_in, const int* in_sizes, int n_in,
                              void* d_out, int out_size, void* d_ws, size_t ws_size,
                              hipStream_t stream) {
  const float* x  = (const float*)d_in[0];
  const float* w  = (const float*)d_in[1];
  const int* tgt  = (const int*)d_in[2];
  float* out      = (float*)d_out;

  // workspace: xp (512K) | gsum (128K) | cos_t/phi_t (4K) | [1MB:] wp (102.4M)
  __bf16* xp   = (__bf16*)d_ws;
  float* gsum  = (float*)((char*)d_ws + (size_t)NB * ND * 2);
  float* cos_t = gsum + (size_t)REP * NB;
  float* phi_t = cos_t + NB;
  const size_t WPOFF   = 1 << 20;
  const size_t WPBYTES = (size_t)NTILE * NCHUNK * 4096;   // 102,432,768
  __bf16* wp = (__bf16*)((char*)d_ws + WPOFF);

  hipMemsetAsync(gsum, 0, (size_t)REP * NB * sizeof(float), stream);
  pack_x_kernel<<<NB, 128, 0, stream>>>(x, xp);
  cosphi_kernel<<<NB, 64, 0, stream>>>(x, w, tgt, cos_t, phi_t);
  if (ws_size >= WPOFF + WPBYTES) {
    gemm_lse_kernel<<<NTILE, 512, 0, stream>>>(xp, w, wp, gsum);
  } else {
    gemm_lse_fb<<<NTILE, 512, 0, stream>>>(xp, w, gsum);
  }
  finalize_kernel<<<1, 512, 0, stream>>>(gsum, cos_t, phi_t, out);
}